// Round 1
// baseline (422.710 us; speedup 1.0000x reference)
//
#include <hip/hip_runtime.h>

typedef __attribute__((ext_vector_type(8))) short bf16x8;
typedef __attribute__((ext_vector_type(4))) float f32x4;

#define NWIN 832
#define N1_ 256
#define N2_ 576
#define O1SZ 8388608   // 2*128*128*256

__device__ __forceinline__ ushort f2bf(float f) {
    union { float f; unsigned u; } v; v.f = f;
    unsigned r = v.u + 0x7fffu + ((v.u >> 16) & 1u);
    return (ushort)(r >> 16);
}

// ---------------- prep: transpose / convert weights ----------------
// m=0: WvT[n][k] = bf16(W_v[k][ j(n) ]), j = ((n&31)<<3)|(n>>5)  (output cols h-major)
// m=1: WvbT[d][c] = bf16(W_vb[c][d])
// m=2: WqkT[c][k] = W_qk[k][c]  (f32)
__global__ __launch_bounds__(256) void k_prep(const float* __restrict__ W_qk,
        const float* __restrict__ W_v, const float* __restrict__ W_vb,
        ushort* __restrict__ WvT, ushort* __restrict__ WvbT, float* __restrict__ WqkT)
{
    int row = blockIdx.x & 255, m = blockIdx.x >> 8, t = threadIdx.x;
    if (m == 0) {
        int j = ((row & 31) << 3) | (row >> 5);
        WvT[row * 256 + t] = f2bf(W_v[t * 256 + j]);
    } else if (m == 1) {
        WvbT[row * 256 + t] = f2bf(W_vb[t * 256 + row]);
    } else {
        WqkT[row * 256 + t] = W_qk[t * 256 + row];
    }
}

// ---------------- K1: window staging + avg + V projection ----------------
// block = one (b, win). 256 thr. out: avg f32 [b][win][256], vattn bf16 [b][h][win][i*32+e]
__global__ __launch_bounds__(256) void k_projv(const float* __restrict__ x1, const float* __restrict__ x2,
        const ushort* __restrict__ WvT, float* __restrict__ avg, ushort* __restrict__ vattn)
{
    __shared__ ushort a_lds[64][264];
    int bid = blockIdx.x, b = bid / NWIN, win = bid % NWIN;
    const float* src; int Wd, base;
    if (win < N1_) { src = x1; Wd = 128; int wh = win >> 4, ww = win & 15;
                     base = ((b*128 + wh*8)*128 + ww*8)*256; }
    else           { src = x2; Wd = 192; int w2 = win - N1_; int wh = w2/24, ww = w2%24;
                     base = ((b*192 + wh*8)*192 + ww*8)*256; }
    int c = threadIdx.x;
    float s = 0.f;
    #pragma unroll 8
    for (int i = 0; i < 64; ++i) {
        float g = src[base + ((i>>3)*Wd + (i&7))*256 + c];
        s += g;
        a_lds[i][c] = f2bf(g);
    }
    avg[(b*NWIN + win)*256 + c] = s * 0.015625f;
    __syncthreads();

    int lane = threadIdx.x & 63, wv = threadIdx.x >> 6;
    int lr = lane & 15, lg = lane >> 4;
    f32x4 acc[4][4];
    #pragma unroll
    for (int mt=0;mt<4;++mt)
      #pragma unroll
      for (int nt=0;nt<4;++nt) acc[mt][nt] = (f32x4){0.f,0.f,0.f,0.f};

    #pragma unroll 2
    for (int ks = 0; ks < 8; ++ks) {
        bf16x8 af[4], bfr[4];
        #pragma unroll
        for (int mt=0;mt<4;++mt) af[mt] = *(const bf16x8*)&a_lds[mt*16 + lr][ks*32 + lg*8];
        #pragma unroll
        for (int nt=0;nt<4;++nt) bfr[nt] = *(const bf16x8*)&WvT[(wv*64 + nt*16 + lr)*256 + ks*32 + lg*8];
        #pragma unroll
        for (int mt=0;mt<4;++mt)
          #pragma unroll
          for (int nt=0;nt<4;++nt)
            acc[mt][nt] = __builtin_amdgcn_mfma_f32_16x16x32_bf16(af[mt], bfr[nt], acc[mt][nt], 0, 0, 0);
    }
    #pragma unroll
    for (int nt=0;nt<4;++nt) {
        int ncol = wv*64 + nt*16 + lr, h = ncol >> 5, e = ncol & 31;
        ushort* pb = &vattn[((size_t)(b*8 + h)*NWIN + win)*2048 + e];
        #pragma unroll
        for (int mt=0;mt<4;++mt)
          #pragma unroll
          for (int r=0;r<4;++r) {
            int i = mt*16 + lg*4 + r;
            pb[i*32] = f2bf(acc[mt][nt][r]);
          }
    }
}

// ---------------- K2: qk = rmsnorm(avg @ W_qk + b) * w ----------------
// block = one (b,win) row. q/k f32 [b][h][win][16]
__global__ __launch_bounds__(256) void k_qk(const float* __restrict__ avg, const float* __restrict__ WqkT,
        const float* __restrict__ b_qk, const float* __restrict__ rms_w,
        float* __restrict__ qv, float* __restrict__ kv)
{
    __shared__ float arow[256];
    __shared__ float red[256];
    int row = blockIdx.x, c = threadIdx.x;
    arow[c] = avg[row*256 + c];
    __syncthreads();
    const float4* wr = (const float4*)&WqkT[c*256];
    float t = 0.f;
    #pragma unroll 8
    for (int k4 = 0; k4 < 64; ++k4) {
        float4 w = wr[k4];
        t += arow[k4*4]*w.x + arow[k4*4+1]*w.y + arow[k4*4+2]*w.z + arow[k4*4+3]*w.w;
    }
    t += b_qk[c];
    red[c] = t*t;
    __syncthreads();
    for (int s = 128; s; s >>= 1) { if (c < s) red[c] += red[c+s]; __syncthreads(); }
    float ms = red[0] * (1.f/256.f);
    float y = t * rsqrtf(ms + 1e-6f) * rms_w[c];
    int b = row / NWIN, win = row % NWIN;
    int h = c >> 5, sub = c & 31;
    size_t ob = ((size_t)(b*8 + h)*NWIN + win)*16 + (sub & 15);
    if (sub < 16) qv[ob] = y; else kv[ob] = y;
}

// ---------------- K3: scores (cross-source only) + softmax -> A bf16 ----------------
// block = one (b,h,q) row. A layout per bh: A1[256][576] then A2[576][256]
__global__ __launch_bounds__(256) void k_sm(const float* __restrict__ qv, const float* __restrict__ kv,
        ushort* __restrict__ Amat)
{
    __shared__ float red[256];
    int rowid = blockIdx.x;
    int qg = rowid % NWIN, bh = rowid / NWIN;
    bool s1 = qg < N1_;
    int Nk = s1 ? N2_ : N1_;
    int kbase = s1 ? N1_ : 0;
    size_t Abase = (size_t)bh*294912 + (s1 ? (size_t)qg*576 : (147456 + (size_t)(qg - N1_)*256));
    const float4* qp = (const float4*)&qv[((size_t)bh*NWIN + qg)*16];
    float4 q0 = qp[0], q1 = qp[1], q2 = qp[2], q3 = qp[3];
    const float* kp = &kv[((size_t)bh*NWIN + kbase)*16];
    int t = threadIdx.x;
    float sc[3];
    #pragma unroll
    for (int it = 0; it < 3; ++it) {
        int kk = t + it*256;
        sc[it] = -1e30f;
        if (kk < Nk) {
            const float4* kr = (const float4*)&kp[(size_t)kk*16];
            float4 a = kr[0], bq = kr[1], cq = kr[2], dq = kr[3];
            float d = q0.x*a.x + q0.y*a.y + q0.z*a.z + q0.w*a.w
                    + q1.x*bq.x + q1.y*bq.y + q1.z*bq.z + q1.w*bq.w
                    + q2.x*cq.x + q2.y*cq.y + q2.z*cq.z + q2.w*cq.w
                    + q3.x*dq.x + q3.y*dq.y + q3.z*dq.z + q3.w*dq.w;
            sc[it] = d * 0.08838834764831845f;
        }
    }
    float m = fmaxf(fmaxf(sc[0], sc[1]), sc[2]);
    red[t] = m; __syncthreads();
    for (int s = 128; s; s >>= 1) { if (t < s) red[t] = fmaxf(red[t], red[t+s]); __syncthreads(); }
    float M = red[0];
    __syncthreads();
    float e0 = __expf(sc[0]-M), e1 = __expf(sc[1]-M), e2 = __expf(sc[2]-M);
    red[t] = e0 + e1 + e2; __syncthreads();
    for (int s = 128; s; s >>= 1) { if (t < s) red[t] += red[t+s]; __syncthreads(); }
    float inv = 1.f / red[0];
    float ex[3] = {e0, e1, e2};
    #pragma unroll
    for (int it = 0; it < 3; ++it) {
        int kk = t + it*256;
        if (kk < Nk) Amat[Abase + kk] = f2bf(ex[it]*inv);
    }
}

// ---------------- K4: out = A @ v  (per b,h,side; tiled MFMA GEMM) ----------------
// grid: 16 bh * 8 fchunk * 13 qchunk(4 side1 + 9 side2) = 1664
__global__ __launch_bounds__(256) void k_av(const ushort* __restrict__ Amat,
        const ushort* __restrict__ vattn, ushort* __restrict__ outc)
{
    __shared__ ushort a_lds[64][40];
    __shared__ ushort v_lds[256][40];
    int bid = blockIdx.x;
    int bh = bid / 104, r = bid % 104, fc = r / 13, qc = r % 13;
    int Nk, kbase, q0, qg0, Astride; size_t Abase;
    if (qc < 4) { Nk = N2_; kbase = N1_; q0 = qc*64; qg0 = q0;
                  Abase = (size_t)bh*294912 + (size_t)q0*576; Astride = 576; }
    else        { Nk = N1_; kbase = 0; q0 = (qc-4)*64; qg0 = N1_ + q0;
                  Abase = (size_t)bh*294912 + 147456 + (size_t)q0*256; Astride = 256; }
    const ushort* vbase = &vattn[((size_t)bh*NWIN + kbase)*2048 + fc*256];
    int t = threadIdx.x;
    int lane = t & 63, wv = t >> 6, lr = lane & 15, lg = lane >> 4;
    f32x4 acc[4][4];
    #pragma unroll
    for (int mt=0;mt<4;++mt)
      #pragma unroll
      for (int nt=0;nt<4;++nt) acc[mt][nt] = (f32x4){0.f,0.f,0.f,0.f};

    int nsteps = Nk >> 5;
    for (int ks = 0; ks < nsteps; ++ks) {
        __syncthreads();
        { // stage A tile (64 q x 32 k)
            int q = t >> 2, seg = t & 3;
            const ushort* gp = &Amat[Abase + (size_t)q*Astride + ks*32 + seg*8];
            *(uint4*)&a_lds[q][seg*8] = *(const uint4*)gp;
        }
        { // stage V tile (32 k x 256 f) transposed with XOR-8-block swizzle on k
            int krow = t >> 3, u = t & 7;
            int kw = krow ^ ((u & 3) << 3);
            const ushort* vp = &vbase[(size_t)(ks*32 + krow)*2048];
            #pragma unroll
            for (int j = 0; j < 4; ++j) {
                int f0 = (u + 8*j) * 8;
                uint4 d = *(const uint4*)&vp[f0];
                const ushort* dv = (const ushort*)&d;
                #pragma unroll
                for (int jj = 0; jj < 8; ++jj) v_lds[f0 + jj][kw] = dv[jj];
            }
        }
        __syncthreads();
        bf16x8 af[4];
        #pragma unroll
        for (int mt=0;mt<4;++mt) af[mt] = *(const bf16x8*)&a_lds[mt*16 + lr][lg*8];
        #pragma unroll
        for (int nt=0;nt<4;++nt) {
            int f = wv*64 + nt*16 + lr;
            int s3r = (f >> 3) & 3;
            bf16x8 bb = *(const bf16x8*)&v_lds[f][(lg ^ s3r) << 3];
            #pragma unroll
            for (int mt=0;mt<4;++mt)
                acc[mt][nt] = __builtin_amdgcn_mfma_f32_16x16x32_bf16(af[mt], bb, acc[mt][nt], 0, 0, 0);
        }
    }
    size_t ob = ((size_t)bh*NWIN + qg0)*2048 + fc*256;
    #pragma unroll
    for (int nt=0;nt<4;++nt) {
        int f = wv*64 + nt*16 + lr;
        #pragma unroll
        for (int mt=0;mt<4;++mt)
          #pragma unroll
          for (int rr=0;rr<4;++rr) {
            int q = mt*16 + lg*4 + rr;
            outc[ob + (size_t)q*2048 + f] = f2bf(acc[mt][nt][rr]);
          }
    }
}

// ---------------- K5: final projection + unwindow ----------------
// block = one (b, win): gather 8 head planes -> LDS[i][e*8+h], GEMM with WvbT, write f32 out
__global__ __launch_bounds__(256) void k_out(const ushort* __restrict__ outc,
        const ushort* __restrict__ WvbT, float* __restrict__ out)
{
    __shared__ ushort a_lds[64][264];
    int bid = blockIdx.x, b = bid / NWIN, win = bid % NWIN;
    int t = threadIdx.x;
    int i_ = (t*8) >> 5, e0 = (t*8) & 31;
    #pragma unroll
    for (int h = 0; h < 8; ++h) {
        const ushort* pp = &outc[((size_t)(b*8 + h)*NWIN + win)*2048 + t*8];
        uint4 d = *(const uint4*)pp;
        const ushort* dv = (const ushort*)&d;
        #pragma unroll
        for (int jj = 0; jj < 8; ++jj) a_lds[i_][(e0 + jj)*8 + h] = dv[jj];
    }
    __syncthreads();

    int lane = t & 63, wv = t >> 6, lr = lane & 15, lg = lane >> 4;
    f32x4 acc[4][4];
    #pragma unroll
    for (int mt=0;mt<4;++mt)
      #pragma unroll
      for (int nt=0;nt<4;++nt) acc[mt][nt] = (f32x4){0.f,0.f,0.f,0.f};

    #pragma unroll 2
    for (int ks = 0; ks < 8; ++ks) {
        bf16x8 af[4], bfr[4];
        #pragma unroll
        for (int mt=0;mt<4;++mt) af[mt] = *(const bf16x8*)&a_lds[mt*16 + lr][ks*32 + lg*8];
        #pragma unroll
        for (int nt=0;nt<4;++nt) bfr[nt] = *(const bf16x8*)&WvbT[(wv*64 + nt*16 + lr)*256 + ks*32 + lg*8];
        #pragma unroll
        for (int mt=0;mt<4;++mt)
          #pragma unroll
          for (int nt=0;nt<4;++nt)
            acc[mt][nt] = __builtin_amdgcn_mfma_f32_16x16x32_bf16(af[mt], bfr[nt], acc[mt][nt], 0, 0, 0);
    }

    int Wd, base;
    if (win < N1_) { Wd = 128; int wh = win >> 4, ww = win & 15;
                     base = ((b*128 + wh*8)*128 + ww*8)*256; }
    else           { Wd = 192; int w2 = win - N1_; int wh = w2/24, ww = w2%24;
                     base = O1SZ + ((b*192 + wh*8)*192 + ww*8)*256; }
    #pragma unroll
    for (int nt=0;nt<4;++nt) {
        int dcol = wv*64 + nt*16 + lr;
        #pragma unroll
        for (int mt=0;mt<4;++mt)
          #pragma unroll
          for (int rr=0;rr<4;++rr) {
            int i = mt*16 + lg*4 + rr;
            out[base + ((i>>3)*Wd + (i&7))*256 + dcol] = acc[mt][nt][rr];
          }
    }
}

// ---------------- launch ----------------
extern "C" void kernel_launch(void* const* d_in, const int* in_sizes, int n_in,
                              void* d_out, int out_size, void* d_ws, size_t ws_size,
                              hipStream_t stream) {
    const float* x1    = (const float*)d_in[0];
    const float* x2    = (const float*)d_in[1];
    const float* W_qk  = (const float*)d_in[2];
    const float* b_qk  = (const float*)d_in[3];
    const float* rms_w = (const float*)d_in[4];
    const float* W_v   = (const float*)d_in[5];
    const float* W_vb  = (const float*)d_in[6];

    char* ws = (char*)d_ws;
    ushort* WvT   = (ushort*)(ws + 0);          //   131072 B
    ushort* WvbT  = (ushort*)(ws + 131072);     //   131072 B
    float*  WqkT  = (float*) (ws + 262144);     //   262144 B
    float*  avg   = (float*) (ws + 524288);     //  1703936 B
    float*  qv    = (float*) (ws + 2228224);    //   851968 B
    float*  kv    = (float*) (ws + 3080192);    //   851968 B
    ushort* vattn = (ushort*)(ws + 3932160);    // 54525952 B
    ushort* Amat  = (ushort*)(ws + 58458112);   //  9437184 B
    ushort* outc  = (ushort*)(ws + 67895296);   // 54525952 B  -> total 122421248 B

    k_prep <<<768,   256, 0, stream>>>(W_qk, W_v, W_vb, WvT, WvbT, WqkT);
    k_projv<<<1664,  256, 0, stream>>>(x1, x2, WvT, avg, vattn);
    k_qk   <<<1664,  256, 0, stream>>>(avg, WqkT, b_qk, rms_w, qv, kv);
    k_sm   <<<13312, 256, 0, stream>>>(qv, kv, Amat);
    k_av   <<<1664,  256, 0, stream>>>(Amat, vattn, outc);
    k_out  <<<1664,  256, 0, stream>>>(outc, WvbT, (float*)d_out);
}

// Round 3
// 410.337 us; speedup vs baseline: 1.0302x; 1.0302x over previous
//
#include <hip/hip_runtime.h>

typedef __attribute__((ext_vector_type(8))) short bf16x8;
typedef __attribute__((ext_vector_type(4))) float f32x4;

#define NWIN 832
#define N1_ 256
#define N2_ 576
#define O1SZ 8388608   // 2*128*128*256

__device__ __forceinline__ ushort f2bf(float f) {
    union { float f; unsigned u; } v; v.f = f;
    unsigned r = v.u + 0x7fffu + ((v.u >> 16) & 1u);
    return (ushort)(r >> 16);
}

// ---------------- prep: transpose / convert weights ----------------
__global__ __launch_bounds__(256) void k_prep(const float* __restrict__ W_qk,
        const float* __restrict__ W_v, const float* __restrict__ W_vb,
        ushort* __restrict__ WvT, ushort* __restrict__ WvbT, float* __restrict__ WqkT)
{
    int row = blockIdx.x & 255, m = blockIdx.x >> 8, t = threadIdx.x;
    if (m == 0) {
        int j = ((row & 31) << 3) | (row >> 5);
        WvT[row * 256 + t] = f2bf(W_v[t * 256 + j]);
    } else if (m == 1) {
        WvbT[row * 256 + t] = f2bf(W_vb[t * 256 + row]);
    } else {
        WqkT[row * 256 + t] = W_qk[t * 256 + row];
    }
}

// ---------------- K1: window staging + avg + V projection ----------------
// block = one (b, win). vattn bf16 layout: [b][h][win][e*64 + i]
__global__ __launch_bounds__(256) void k_projv(const float* __restrict__ x1, const float* __restrict__ x2,
        const ushort* __restrict__ WvT, float* __restrict__ avg, ushort* __restrict__ vattn)
{
    __shared__ __align__(16) char smem[37888];
    ushort (*a_lds)[264] = (ushort (*)[264])smem;          // 33792 B
    float* psumF = (float*)(smem + 33792);                  // 4096 B

    int bid = blockIdx.x, b = bid / NWIN, win = bid % NWIN;
    const float* src; int Wd, base;
    if (win < N1_) { src = x1; Wd = 128; int wh = win >> 4, ww = win & 15;
                     base = ((b*128 + wh*8)*128 + ww*8)*256; }
    else           { src = x2; Wd = 192; int w2 = win - N1_; int wh = w2/24, ww = w2%24;
                     base = ((b*192 + wh*8)*192 + ww*8)*256; }

    int t = threadIdx.x;
    int c4 = t & 63, tg = t >> 6;
    int c0 = c4 * 4;
    const float* sp = src + base + c0;
    float4 s4 = {0.f, 0.f, 0.f, 0.f};
    #pragma unroll
    for (int k = 0; k < 16; ++k) {
        int i = tg*16 + k;
        float4 g = *(const float4*)(sp + ((i>>3)*Wd + (i&7))*256);
        s4.x += g.x; s4.y += g.y; s4.z += g.z; s4.w += g.w;
        ushort4 hb = { f2bf(g.x), f2bf(g.y), f2bf(g.z), f2bf(g.w) };
        *(ushort4*)&a_lds[i][c0] = hb;
    }
    *(float4*)&psumF[tg*256 + c0] = s4;
    __syncthreads();

    {
        float a = psumF[t] + psumF[256 + t] + psumF[512 + t] + psumF[768 + t];
        avg[(b*NWIN + win)*256 + t] = a * 0.015625f;
    }

    int lane = t & 63, wv = t >> 6, lr = lane & 15, lg = lane >> 4;
    f32x4 acc[4][4];
    #pragma unroll
    for (int mt=0;mt<4;++mt)
      #pragma unroll
      for (int nt=0;nt<4;++nt) acc[mt][nt] = (f32x4){0.f,0.f,0.f,0.f};

    #pragma unroll 2
    for (int ks = 0; ks < 8; ++ks) {
        bf16x8 af[4], bfr[4];
        #pragma unroll
        for (int mt=0;mt<4;++mt) af[mt] = *(const bf16x8*)&a_lds[mt*16 + lr][ks*32 + lg*8];
        #pragma unroll
        for (int nt=0;nt<4;++nt) bfr[nt] = *(const bf16x8*)&WvT[(wv*64 + nt*16 + lr)*256 + ks*32 + lg*8];
        #pragma unroll
        for (int mt=0;mt<4;++mt)
          #pragma unroll
          for (int nt=0;nt<4;++nt)
            acc[mt][nt] = __builtin_amdgcn_mfma_f32_16x16x32_bf16(af[mt], bfr[nt], acc[mt][nt], 0, 0, 0);
    }

    __syncthreads();   // a_lds / psum dead; reuse smem for per-wave restage
    ushort (*sw)[72] = (ushort (*)[72])(smem + wv*9216);   // 64 x 72 ushort per wave

    #pragma unroll
    for (int nt=0; nt<4; ++nt) {
        int c = nt*16 + lr;
        #pragma unroll
        for (int mt=0; mt<4; ++mt) {
            ushort4 hb = { f2bf(acc[mt][nt][0]), f2bf(acc[mt][nt][1]),
                           f2bf(acc[mt][nt][2]), f2bf(acc[mt][nt][3]) };
            *(ushort4*)&sw[c][mt*16 + lg*4] = hb;
        }
    }
    #pragma unroll
    for (int u=0; u<2; ++u) {
        int h = wv*2 + u;
        ushort* dst = &vattn[((size_t)(b*8 + h)*NWIN + win)*2048];
        #pragma unroll
        for (int it=0; it<4; ++it) {
            int q = it*64 + lane;
            int e = q >> 3, i8 = (q & 7) * 8;
            *(uint4*)&dst[e*64 + i8] = *(const uint4*)&sw[u*32 + e][i8];
        }
    }
}

// ---------------- K2: qk = rmsnorm(avg @ W_qk + b) * w ----------------
__global__ __launch_bounds__(256) void k_qk(const float* __restrict__ avg, const float* __restrict__ WqkT,
        const float* __restrict__ b_qk, const float* __restrict__ rms_w,
        float* __restrict__ qv, float* __restrict__ kv)
{
    __shared__ float arow[256];
    __shared__ float red[256];
    int row = blockIdx.x, c = threadIdx.x;
    arow[c] = avg[row*256 + c];
    __syncthreads();
    const float4* wr = (const float4*)&WqkT[c*256];
    float t = 0.f;
    #pragma unroll 8
    for (int k4 = 0; k4 < 64; ++k4) {
        float4 w = wr[k4];
        t += arow[k4*4]*w.x + arow[k4*4+1]*w.y + arow[k4*4+2]*w.z + arow[k4*4+3]*w.w;
    }
    t += b_qk[c];
    red[c] = t*t;
    __syncthreads();
    for (int s = 128; s; s >>= 1) { if (c < s) red[c] += red[c+s]; __syncthreads(); }
    float ms = red[0] * (1.f/256.f);
    float y = t * rsqrtf(ms + 1e-6f) * rms_w[c];
    int b = row / NWIN, win = row % NWIN;
    int h = c >> 5, sub = c & 31;
    size_t ob = ((size_t)(b*8 + h)*NWIN + win)*16 + (sub & 15);
    if (sub < 16) qv[ob] = y; else kv[ob] = y;
}

// ---------------- K3: scores (cross-source only) + softmax -> A bf16 ----------------
__global__ __launch_bounds__(256) void k_sm(const float* __restrict__ qv, const float* __restrict__ kv,
        ushort* __restrict__ Amat)
{
    __shared__ float red[256];
    int rowid = blockIdx.x;
    int qg = rowid % NWIN, bh = rowid / NWIN;
    bool s1 = qg < N1_;
    int Nk = s1 ? N2_ : N1_;
    int kbase = s1 ? N1_ : 0;
    size_t Abase = (size_t)bh*294912 + (s1 ? (size_t)qg*576 : (147456 + (size_t)(qg - N1_)*256));
    const float4* qp = (const float4*)&qv[((size_t)bh*NWIN + qg)*16];
    float4 q0 = qp[0], q1 = qp[1], q2 = qp[2], q3 = qp[3];
    const float* kp = &kv[((size_t)bh*NWIN + kbase)*16];
    int t = threadIdx.x;
    float sc[3];
    #pragma unroll
    for (int it = 0; it < 3; ++it) {
        int kk = t + it*256;
        sc[it] = -1e30f;
        if (kk < Nk) {
            const float4* kr = (const float4*)&kp[(size_t)kk*16];
            float4 a = kr[0], bq = kr[1], cq = kr[2], dq = kr[3];
            float d = q0.x*a.x + q0.y*a.y + q0.z*a.z + q0.w*a.w
                    + q1.x*bq.x + q1.y*bq.y + q1.z*bq.z + q1.w*bq.w
                    + q2.x*cq.x + q2.y*cq.y + q2.z*cq.z + q2.w*cq.w
                    + q3.x*dq.x + q3.y*dq.y + q3.z*dq.z + q3.w*dq.w;
            sc[it] = d * 0.08838834764831845f;
        }
    }
    float m = fmaxf(fmaxf(sc[0], sc[1]), sc[2]);
    red[t] = m; __syncthreads();
    for (int s = 128; s; s >>= 1) { if (t < s) red[t] = fmaxf(red[t], red[t+s]); __syncthreads(); }
    float M = red[0];
    __syncthreads();
    float e0 = __expf(sc[0]-M), e1 = __expf(sc[1]-M), e2 = __expf(sc[2]-M);
    red[t] = e0 + e1 + e2; __syncthreads();
    for (int s = 128; s; s >>= 1) { if (t < s) red[t] += red[t+s]; __syncthreads(); }
    float inv = 1.f / red[0];
    float ex[3] = {e0, e1, e2};
    #pragma unroll
    for (int it = 0; it < 3; ++it) {
        int kk = t + it*256;
        if (kk < Nk) Amat[Abase + kk] = f2bf(ex[it]*inv);
    }
}

// ---------------- K4: out = A @ v  (per b,h,side; tiled MFMA GEMM) ----------------
__global__ __launch_bounds__(256) void k_av(const ushort* __restrict__ Amat,
        const ushort* __restrict__ vattn, ushort* __restrict__ outc)
{
    __shared__ ushort a_lds[64][40];
    __shared__ ushort v_lds[256][40];
    int bid = blockIdx.x;
    int bh = bid / 104, r = bid % 104, fc = r / 13, qc = r % 13;
    int Nk, kbase, q0, qg0, Astride; size_t Abase;
    if (qc < 4) { Nk = N2_; kbase = N1_; q0 = qc*64; qg0 = q0;
                  Abase = (size_t)bh*294912 + (size_t)q0*576; Astride = 576; }
    else        { Nk = N1_; kbase = 0; q0 = (qc-4)*64; qg0 = N1_ + q0;
                  Abase = (size_t)bh*294912 + 147456 + (size_t)q0*256; Astride = 256; }
    const ushort* vbase = &vattn[((size_t)bh*NWIN + kbase)*2048 + fc*256];
    int t = threadIdx.x;
    int lane = t & 63, wv = t >> 6, lr = lane & 15, lg = lane >> 4;
    f32x4 acc[4][4];
    #pragma unroll
    for (int mt=0;mt<4;++mt)
      #pragma unroll
      for (int nt=0;nt<4;++nt) acc[mt][nt] = (f32x4){0.f,0.f,0.f,0.f};

    int nsteps = Nk >> 5;
    for (int ks = 0; ks < nsteps; ++ks) {
        __syncthreads();
        { // stage A tile (64 q x 32 k)
            int q = t >> 2, seg = t & 3;
            const ushort* gp = &Amat[Abase + (size_t)q*Astride + ks*32 + seg*8];
            *(uint4*)&a_lds[q][seg*8] = *(const uint4*)gp;
        }
        { // stage V tile (32 k x 256 f), transposed, row-pair ushort2 writes
            int u = t & 7, rp = (t >> 3) & 15, half = t >> 7;
            int k0 = rp * 2;
            int kw = k0 ^ ((u & 3) << 3);
            const ushort* vp0 = &vbase[(size_t)(ks*32 + k0)*2048];
            const ushort* vp1 = vp0 + 2048;
            #pragma unroll
            for (int j = 0; j < 2; ++j) {
                int f0 = (u + 8*(half*2 + j)) * 8;
                uint4 d0 = *(const uint4*)&vp0[f0];
                uint4 d1 = *(const uint4*)&vp1[f0];
                const ushort* a0 = (const ushort*)&d0;
                const ushort* a1 = (const ushort*)&d1;
                #pragma unroll
                for (int jj = 0; jj < 8; ++jj) {
                    ushort2 w2 = { a0[jj], a1[jj] };
                    *(ushort2*)&v_lds[f0 + jj][kw] = w2;
                }
            }
        }
        __syncthreads();
        bf16x8 af[4];
        #pragma unroll
        for (int mt=0;mt<4;++mt) af[mt] = *(const bf16x8*)&a_lds[mt*16 + lr][lg*8];
        #pragma unroll
        for (int nt=0;nt<4;++nt) {
            int f = wv*64 + nt*16 + lr;
            int s3r = (f >> 3) & 3;
            bf16x8 bb = *(const bf16x8*)&v_lds[f][(lg ^ s3r) << 3];
            #pragma unroll
            for (int mt=0;mt<4;++mt)
                acc[mt][nt] = __builtin_amdgcn_mfma_f32_16x16x32_bf16(af[mt], bb, acc[mt][nt], 0, 0, 0);
        }
    }
    size_t ob = ((size_t)bh*NWIN + qg0)*2048 + fc*256;
    #pragma unroll
    for (int nt=0;nt<4;++nt) {
        int f = wv*64 + nt*16 + lr;
        #pragma unroll
        for (int mt=0;mt<4;++mt)
          #pragma unroll
          for (int rr=0;rr<4;++rr) {
            int q = mt*16 + lg*4 + rr;
            outc[ob + (size_t)q*2048 + f] = f2bf(acc[mt][nt][rr]);
          }
    }
}

// ---------------- K5: final projection + unwindow ----------------
__global__ __launch_bounds__(256) void k_out(const ushort* __restrict__ outc,
        const ushort* __restrict__ WvbT, float* __restrict__ out)
{
    __shared__ ushort a_lds[64][264];
    int bid = blockIdx.x, b = bid / NWIN, win = bid % NWIN;
    int t = threadIdx.x;
    int e = t >> 3, i0 = (t & 7) * 8;
    #pragma unroll
    for (int hg = 0; hg < 2; ++hg) {
        uint4 d[4];
        #pragma unroll
        for (int hh = 0; hh < 4; ++hh)
            d[hh] = *(const uint4*)&outc[((size_t)(b*8 + hg*4 + hh)*NWIN + win)*2048 + t*8];
        const ushort* p0 = (const ushort*)&d[0];
        const ushort* p1 = (const ushort*)&d[1];
        const ushort* p2 = (const ushort*)&d[2];
        const ushort* p3 = (const ushort*)&d[3];
        #pragma unroll
        for (int jj = 0; jj < 8; ++jj) {
            ushort4 w = { p0[jj], p1[jj], p2[jj], p3[jj] };
            *(ushort4*)&a_lds[i0 + jj][e*8 + hg*4] = w;
        }
    }
    __syncthreads();

    int lane = t & 63, wv = t >> 6, lr = lane & 15, lg = lane >> 4;
    f32x4 acc[4][4];
    #pragma unroll
    for (int mt=0;mt<4;++mt)
      #pragma unroll
      for (int nt=0;nt<4;++nt) acc[mt][nt] = (f32x4){0.f,0.f,0.f,0.f};

    #pragma unroll 2
    for (int ks = 0; ks < 8; ++ks) {
        bf16x8 af[4], bfr[4];
        #pragma unroll
        for (int mt=0;mt<4;++mt) af[mt] = *(const bf16x8*)&a_lds[mt*16 + lr][ks*32 + lg*8];
        #pragma unroll
        for (int nt=0;nt<4;++nt) bfr[nt] = *(const bf16x8*)&WvbT[(wv*64 + nt*16 + lr)*256 + ks*32 + lg*8];
        #pragma unroll
        for (int mt=0;mt<4;++mt)
          #pragma unroll
          for (int nt=0;nt<4;++nt)
            acc[mt][nt] = __builtin_amdgcn_mfma_f32_16x16x32_bf16(af[mt], bfr[nt], acc[mt][nt], 0, 0, 0);
    }

    int Wd, base;
    if (win < N1_) { Wd = 128; int wh = win >> 4, ww = win & 15;
                     base = ((b*128 + wh*8)*128 + ww*8)*256; }
    else           { Wd = 192; int w2 = win - N1_; int wh = w2/24, ww = w2%24;
                     base = O1SZ + ((b*192 + wh*8)*192 + ww*8)*256; }
    #pragma unroll
    for (int nt=0;nt<4;++nt) {
        int dcol = wv*64 + nt*16 + lr;
        #pragma unroll
        for (int mt=0;mt<4;++mt)
          #pragma unroll
          for (int rr=0;rr<4;++rr) {
            int i = mt*16 + lg*4 + rr;
            out[base + ((i>>3)*Wd + (i&7))*256 + dcol] = acc[mt][nt][rr];
          }
    }
}

// ---------------- launch ----------------
extern "C" void kernel_launch(void* const* d_in, const int* in_sizes, int n_in,
                              void* d_out, int out_size, void* d_ws, size_t ws_size,
                              hipStream_t stream) {
    const float* x1    = (const float*)d_in[0];
    const float* x2    = (const float*)d_in[1];
    const float* W_qk  = (const float*)d_in[2];
    const float* b_qk  = (const float*)d_in[3];
    const float* rms_w = (const float*)d_in[4];
    const float* W_v   = (const float*)d_in[5];
    const float* W_vb  = (const float*)d_in[6];

    char* ws = (char*)d_ws;
    ushort* WvT   = (ushort*)(ws + 0);          //   131072 B
    ushort* WvbT  = (ushort*)(ws + 131072);     //   131072 B
    float*  WqkT  = (float*) (ws + 262144);     //   262144 B
    float*  avg   = (float*) (ws + 524288);     //  1703936 B
    float*  qv    = (float*) (ws + 2228224);    //   851968 B
    float*  kv    = (float*) (ws + 3080192);    //   851968 B
    ushort* vattn = (ushort*)(ws + 3932160);    // 54525952 B
    ushort* Amat  = (ushort*)(ws + 58458112);   //  9437184 B
    ushort* outc  = (ushort*)(ws + 67895296);   // 54525952 B

    k_prep <<<768,   256, 0, stream>>>(W_qk, W_v, W_vb, WvT, WvbT, WqkT);
    k_projv<<<1664,  256, 0, stream>>>(x1, x2, WvT, avg, vattn);
    k_qk   <<<1664,  256, 0, stream>>>(avg, WqkT, b_qk, rms_w, qv, kv);
    k_sm   <<<13312, 256, 0, stream>>>(qv, kv, Amat);
    k_av   <<<1664,  256, 0, stream>>>(Amat, vattn, outc);
    k_out  <<<1664,  256, 0, stream>>>(outc, WvbT, (float*)d_out);
}

// Round 4
// 386.889 us; speedup vs baseline: 1.0926x; 1.0606x over previous
//
#include <hip/hip_runtime.h>

typedef __attribute__((ext_vector_type(8))) short bf16x8;
typedef __attribute__((ext_vector_type(4))) float f32x4;

#define NWIN 832
#define N1_ 256
#define N2_ 576
#define O1SZ 8388608   // 2*128*128*256

__device__ __forceinline__ ushort f2bf(float f) {
    union { float f; unsigned u; } v; v.f = f;
    unsigned r = v.u + 0x7fffu + ((v.u >> 16) & 1u);
    return (ushort)(r >> 16);
}

// ---------------- prep: transpose / convert weights ----------------
__global__ __launch_bounds__(256) void k_prep(const float* __restrict__ W_qk,
        const float* __restrict__ W_v, const float* __restrict__ W_vb,
        ushort* __restrict__ WvT, ushort* __restrict__ WvbT, float* __restrict__ WqkT)
{
    int row = blockIdx.x & 255, m = blockIdx.x >> 8, t = threadIdx.x;
    if (m == 0) {
        int j = ((row & 31) << 3) | (row >> 5);
        WvT[row * 256 + t] = f2bf(W_v[t * 256 + j]);
    } else if (m == 1) {
        WvbT[row * 256 + t] = f2bf(W_vb[t * 256 + row]);
    } else {
        WqkT[row * 256 + t] = W_qk[t * 256 + row];
    }
}

// ---------------- K1: window staging + avg + V projection ----------------
// 512 threads = 8 waves; wave wv computes n-cols [wv*32, wv*32+32) = head wv.
// LDS: 32 KB XOR-swizzled A-tile (64 tok x 256 ch bf16); reused as per-wave
// restage buffer (8 x 4 KB) for coalesced vattn stores.
__global__ __launch_bounds__(512) void k_projv(const float* __restrict__ x1, const float* __restrict__ x2,
        const ushort* __restrict__ WvT, float* __restrict__ avg, ushort* __restrict__ vattn)
{
    __shared__ __align__(16) char smem[32768];

    int bid = blockIdx.x, b = bid / NWIN, win = bid % NWIN;
    const float* src; int Wd, base;
    if (win < N1_) { src = x1; Wd = 128; int wh = win >> 4, ww = win & 15;
                     base = ((b*128 + wh*8)*128 + ww*8)*256; }
    else           { src = x2; Wd = 192; int w2 = win - N1_; int wh = w2/24, ww = w2%24;
                     base = ((b*192 + wh*8)*192 + ww*8)*256; }

    int t = threadIdx.x;
    int wv = t >> 6, lane = t & 63;
    int c0 = lane * 4;
    const float* sp = src + base + c0;

    // phase 1: batched loads (all 8 in flight before first use), then convert+LDS
    float4 r[8];
    #pragma unroll
    for (int k = 0; k < 8; ++k) {
        int i = wv*8 + k;
        r[k] = *(const float4*)(sp + ((i>>3)*Wd + (i&7))*256);
    }
    #pragma unroll
    for (int k = 0; k < 8; ++k) {
        int i = wv*8 + k;
        ushort4 hb = { f2bf(r[k].x), f2bf(r[k].y), f2bf(r[k].z), f2bf(r[k].w) };
        unsigned off = (unsigned)(i*512 + c0*2) ^ ((unsigned)(i&7) << 4);
        *(ushort4*)(smem + off) = hb;
    }
    __syncthreads();

    // phase 2: avg from bf16 tile (threads 0..255, channel = t)
    if (t < 256) {
        float s = 0.f;
        #pragma unroll
        for (int i = 0; i < 64; ++i) {
            unsigned off = (unsigned)(i*512 + t*2) ^ ((unsigned)(i&7) << 4);
            ushort u = *(const ushort*)(smem + off);
            union { unsigned u; float f; } cv; cv.u = (unsigned)u << 16;
            s += cv.f;
        }
        avg[(b*NWIN + win)*256 + t] = s * 0.015625f;
    }

    // phase 3: MFMA — wave wv covers 32 n-cols (= head wv)
    int lr = lane & 15, lg = lane >> 4;
    unsigned axor = ((unsigned)(lr & 7)) << 4;
    f32x4 acc[4][2];
    #pragma unroll
    for (int mt=0;mt<4;++mt)
      #pragma unroll
      for (int nt=0;nt<2;++nt) acc[mt][nt] = (f32x4){0.f,0.f,0.f,0.f};

    #pragma unroll 2
    for (int ks = 0; ks < 8; ++ks) {
        bf16x8 bfr[2], af[4];
        #pragma unroll
        for (int nt=0;nt<2;++nt)
            bfr[nt] = *(const bf16x8*)&WvT[(wv*32 + nt*16 + lr)*256 + ks*32 + lg*8];
        #pragma unroll
        for (int mt=0;mt<4;++mt) {
            unsigned off = ((unsigned)((mt*16+lr)*512 + ks*64 + lg*16)) ^ axor;
            af[mt] = *(const bf16x8*)(smem + off);
        }
        #pragma unroll
        for (int mt=0;mt<4;++mt)
          #pragma unroll
          for (int nt=0;nt<2;++nt)
            acc[mt][nt] = __builtin_amdgcn_mfma_f32_16x16x32_bf16(af[mt], bfr[nt], acc[mt][nt], 0, 0, 0);
    }
    __syncthreads();   // tile dead; smem becomes 8 x 4KB per-wave restage

    // phase 4: per-wave swizzled restage -> coalesced 1KB stores
    char* swb = smem + wv*4096;    // [32 cols][64 tok] bf16, 16B-block XOR swizzle
    #pragma unroll
    for (int nt=0; nt<2; ++nt) {
        int c = nt*16 + lr;
        unsigned cx = ((unsigned)(c & 7)) << 4;
        #pragma unroll
        for (int mt=0; mt<4; ++mt) {
            ushort4 hb = { f2bf(acc[mt][nt][0]), f2bf(acc[mt][nt][1]),
                           f2bf(acc[mt][nt][2]), f2bf(acc[mt][nt][3]) };
            unsigned off = ((unsigned)(c*128 + (mt*16 + lg*4)*2)) ^ cx;
            *(ushort4*)(swb + off) = hb;
        }
    }
    ushort* dst = &vattn[((size_t)(b*8 + wv)*NWIN + win)*2048];
    #pragma unroll
    for (int it=0; it<4; ++it) {
        int q = it*64 + lane;
        int e = q >> 3, i0 = (q & 7) * 8;
        unsigned off = ((unsigned)(e*128 + i0*2)) ^ (((unsigned)(e & 7)) << 4);
        *(uint4*)&dst[e*64 + i0] = *(const uint4*)(swb + off);
    }
}

// ---------------- K2: qk = rmsnorm(avg @ W_qk + b) * w ----------------
__global__ __launch_bounds__(256) void k_qk(const float* __restrict__ avg, const float* __restrict__ WqkT,
        const float* __restrict__ b_qk, const float* __restrict__ rms_w,
        float* __restrict__ qv, float* __restrict__ kv)
{
    __shared__ float arow[256];
    __shared__ float red[256];
    int row = blockIdx.x, c = threadIdx.x;
    arow[c] = avg[row*256 + c];
    __syncthreads();
    const float4* wr = (const float4*)&WqkT[c*256];
    float t = 0.f;
    #pragma unroll 8
    for (int k4 = 0; k4 < 64; ++k4) {
        float4 w = wr[k4];
        t += arow[k4*4]*w.x + arow[k4*4+1]*w.y + arow[k4*4+2]*w.z + arow[k4*4+3]*w.w;
    }
    t += b_qk[c];
    red[c] = t*t;
    __syncthreads();
    for (int s = 128; s; s >>= 1) { if (c < s) red[c] += red[c+s]; __syncthreads(); }
    float ms = red[0] * (1.f/256.f);
    float y = t * rsqrtf(ms + 1e-6f) * rms_w[c];
    int b = row / NWIN, win = row % NWIN;
    int h = c >> 5, sub = c & 31;
    size_t ob = ((size_t)(b*8 + h)*NWIN + win)*16 + (sub & 15);
    if (sub < 16) qv[ob] = y; else kv[ob] = y;
}

// ---------------- K3: scores + softmax -> A bf16 (8 q-rows/block, K in LDS) ----------------
template<int SIDE1>
__global__ __launch_bounds__(256) void k_sm_t(const float* __restrict__ qv,
        const float* __restrict__ kv, ushort* __restrict__ Amat)
{
    constexpr int NK    = SIDE1 ? 576 : 256;
    constexpr int KBASE = SIDE1 ? 256 : 0;
    constexpr int NJ    = NK / 32;
    __shared__ __align__(16) float K_lds[NK*20];
    __shared__ __align__(16) float q_lds[8*16];

    int bid = blockIdx.x;
    int nqc = SIDE1 ? 32 : 72;
    int bh = bid / nqc, qc = bid % nqc;
    int q0 = qc * 8;
    int qgw = SIDE1 ? q0 : (N1_ + q0);
    size_t Abase = (size_t)bh*294912 + (SIDE1 ? (size_t)q0*576 : (147456 + (size_t)q0*256));

    int t = threadIdx.x;
    const float4* kf = (const float4*)&kv[((size_t)bh*NWIN + KBASE)*16];
    #pragma unroll
    for (int jj = 0; jj < (NK*4)/256; ++jj) {
        int idx = t + jj*256;
        float4 v = kf[idx];
        int row = idx >> 2, piece = idx & 3;
        *(float4*)&K_lds[row*20 + piece*4] = v;
    }
    if (t < 32) {
        float4 v = ((const float4*)&qv[((size_t)bh*NWIN + qgw)*16])[t];
        *(float4*)&q_lds[t*4] = v;
    }
    __syncthreads();

    int rr = t >> 5, l = t & 31;
    float q[16];
    #pragma unroll
    for (int c=0;c<16;++c) q[c] = q_lds[rr*16 + c];

    float sc[NJ];
    float m = -1e30f;
    #pragma unroll
    for (int j = 0; j < NJ; ++j) {
        const float4* kr = (const float4*)&K_lds[(l + 32*j)*20];
        float4 a = kr[0], bq = kr[1], cq = kr[2], dq = kr[3];
        float d = q[0]*a.x + q[1]*a.y + q[2]*a.z + q[3]*a.w
                + q[4]*bq.x + q[5]*bq.y + q[6]*bq.z + q[7]*bq.w
                + q[8]*cq.x + q[9]*cq.y + q[10]*cq.z + q[11]*cq.w
                + q[12]*dq.x + q[13]*dq.y + q[14]*dq.z + q[15]*dq.w;
        d *= 0.08838834764831845f;
        sc[j] = d; m = fmaxf(m, d);
    }
    #pragma unroll
    for (int s = 16; s; s >>= 1) m = fmaxf(m, __shfl_xor(m, s));
    float sum = 0.f;
    #pragma unroll
    for (int j = 0; j < NJ; ++j) { sc[j] = __expf(sc[j] - m); sum += sc[j]; }
    #pragma unroll
    for (int s = 16; s; s >>= 1) sum += __shfl_xor(sum, s);
    float inv = 1.f / sum;
    ushort* arow = &Amat[Abase + (size_t)rr*NK];
    #pragma unroll
    for (int j = 0; j < NJ; ++j) arow[l + 32*j] = f2bf(sc[j]*inv);
}

// ---------------- K4: out = A @ v  (per b,h,side; tiled MFMA GEMM) ----------------
__global__ __launch_bounds__(256) void k_av(const ushort* __restrict__ Amat,
        const ushort* __restrict__ vattn, ushort* __restrict__ outc)
{
    __shared__ ushort a_lds[64][40];
    __shared__ ushort v_lds[256][40];
    int bid = blockIdx.x;
    int bh = bid / 104, r = bid % 104, fc = r / 13, qc = r % 13;
    int Nk, kbase, q0, qg0, Astride; size_t Abase;
    if (qc < 4) { Nk = N2_; kbase = N1_; q0 = qc*64; qg0 = q0;
                  Abase = (size_t)bh*294912 + (size_t)q0*576; Astride = 576; }
    else        { Nk = N1_; kbase = 0; q0 = (qc-4)*64; qg0 = N1_ + q0;
                  Abase = (size_t)bh*294912 + 147456 + (size_t)q0*256; Astride = 256; }
    const ushort* vbase = &vattn[((size_t)bh*NWIN + kbase)*2048 + fc*256];
    int t = threadIdx.x;
    int lane = t & 63, wv = t >> 6, lr = lane & 15, lg = lane >> 4;
    f32x4 acc[4][4];
    #pragma unroll
    for (int mt=0;mt<4;++mt)
      #pragma unroll
      for (int nt=0;nt<4;++nt) acc[mt][nt] = (f32x4){0.f,0.f,0.f,0.f};

    int nsteps = Nk >> 5;
    for (int ks = 0; ks < nsteps; ++ks) {
        __syncthreads();
        {
            int q = t >> 2, seg = t & 3;
            const ushort* gp = &Amat[Abase + (size_t)q*Astride + ks*32 + seg*8];
            *(uint4*)&a_lds[q][seg*8] = *(const uint4*)gp;
        }
        {
            int u = t & 7, rp = (t >> 3) & 15, half = t >> 7;
            int k0 = rp * 2;
            int kw = k0 ^ ((u & 3) << 3);
            const ushort* vp0 = &vbase[(size_t)(ks*32 + k0)*2048];
            const ushort* vp1 = vp0 + 2048;
            #pragma unroll
            for (int j = 0; j < 2; ++j) {
                int f0 = (u + 8*(half*2 + j)) * 8;
                uint4 d0 = *(const uint4*)&vp0[f0];
                uint4 d1 = *(const uint4*)&vp1[f0];
                const ushort* a0 = (const ushort*)&d0;
                const ushort* a1 = (const ushort*)&d1;
                #pragma unroll
                for (int jj = 0; jj < 8; ++jj) {
                    ushort2 w2 = { a0[jj], a1[jj] };
                    *(ushort2*)&v_lds[f0 + jj][kw] = w2;
                }
            }
        }
        __syncthreads();
        bf16x8 af[4];
        #pragma unroll
        for (int mt=0;mt<4;++mt) af[mt] = *(const bf16x8*)&a_lds[mt*16 + lr][lg*8];
        #pragma unroll
        for (int nt=0;nt<4;++nt) {
            int f = wv*64 + nt*16 + lr;
            int s3r = (f >> 3) & 3;
            bf16x8 bb = *(const bf16x8*)&v_lds[f][(lg ^ s3r) << 3];
            #pragma unroll
            for (int mt=0;mt<4;++mt)
                acc[mt][nt] = __builtin_amdgcn_mfma_f32_16x16x32_bf16(af[mt], bb, acc[mt][nt], 0, 0, 0);
        }
    }
    size_t ob = ((size_t)bh*NWIN + qg0)*2048 + fc*256;
    #pragma unroll
    for (int nt=0;nt<4;++nt) {
        int f = wv*64 + nt*16 + lr;
        #pragma unroll
        for (int mt=0;mt<4;++mt)
          #pragma unroll
          for (int rr=0;rr<4;++rr) {
            int q = mt*16 + lg*4 + rr;
            outc[ob + (size_t)q*2048 + f] = f2bf(acc[mt][nt][rr]);
          }
    }
}

// ---------------- K5: final projection + unwindow ----------------
__global__ __launch_bounds__(256) void k_out(const ushort* __restrict__ outc,
        const ushort* __restrict__ WvbT, float* __restrict__ out)
{
    __shared__ ushort a_lds[64][264];
    int bid = blockIdx.x, b = bid / NWIN, win = bid % NWIN;
    int t = threadIdx.x;
    int e = t >> 3, i0 = (t & 7) * 8;
    #pragma unroll
    for (int hg = 0; hg < 2; ++hg) {
        uint4 d[4];
        #pragma unroll
        for (int hh = 0; hh < 4; ++hh)
            d[hh] = *(const uint4*)&outc[((size_t)(b*8 + hg*4 + hh)*NWIN + win)*2048 + t*8];
        const ushort* p0 = (const ushort*)&d[0];
        const ushort* p1 = (const ushort*)&d[1];
        const ushort* p2 = (const ushort*)&d[2];
        const ushort* p3 = (const ushort*)&d[3];
        #pragma unroll
        for (int jj = 0; jj < 8; ++jj) {
            ushort4 w = { p0[jj], p1[jj], p2[jj], p3[jj] };
            *(ushort4*)&a_lds[i0 + jj][e*8 + hg*4] = w;
        }
    }
    __syncthreads();

    int lane = t & 63, wv = t >> 6, lr = lane & 15, lg = lane >> 4;
    f32x4 acc[4][4];
    #pragma unroll
    for (int mt=0;mt<4;++mt)
      #pragma unroll
      for (int nt=0;nt<4;++nt) acc[mt][nt] = (f32x4){0.f,0.f,0.f,0.f};

    #pragma unroll 2
    for (int ks = 0; ks < 8; ++ks) {
        bf16x8 af[4], bfr[4];
        #pragma unroll
        for (int mt=0;mt<4;++mt) af[mt] = *(const bf16x8*)&a_lds[mt*16 + lr][ks*32 + lg*8];
        #pragma unroll
        for (int nt=0;nt<4;++nt) bfr[nt] = *(const bf16x8*)&WvbT[(wv*64 + nt*16 + lr)*256 + ks*32 + lg*8];
        #pragma unroll
        for (int mt=0;mt<4;++mt)
          #pragma unroll
          for (int nt=0;nt<4;++nt)
            acc[mt][nt] = __builtin_amdgcn_mfma_f32_16x16x32_bf16(af[mt], bfr[nt], acc[mt][nt], 0, 0, 0);
    }

    int Wd, base;
    if (win < N1_) { Wd = 128; int wh = win >> 4, ww = win & 15;
                     base = ((b*128 + wh*8)*128 + ww*8)*256; }
    else           { Wd = 192; int w2 = win - N1_; int wh = w2/24, ww = w2%24;
                     base = O1SZ + ((b*192 + wh*8)*192 + ww*8)*256; }
    #pragma unroll
    for (int nt=0;nt<4;++nt) {
        int dcol = wv*64 + nt*16 + lr;
        #pragma unroll
        for (int mt=0;mt<4;++mt)
          #pragma unroll
          for (int rr=0;rr<4;++rr) {
            int i = mt*16 + lg*4 + rr;
            out[base + ((i>>3)*Wd + (i&7))*256 + dcol] = acc[mt][nt][rr];
          }
    }
}

// ---------------- launch ----------------
extern "C" void kernel_launch(void* const* d_in, const int* in_sizes, int n_in,
                              void* d_out, int out_size, void* d_ws, size_t ws_size,
                              hipStream_t stream) {
    const float* x1    = (const float*)d_in[0];
    const float* x2    = (const float*)d_in[1];
    const float* W_qk  = (const float*)d_in[2];
    const float* b_qk  = (const float*)d_in[3];
    const float* rms_w = (const float*)d_in[4];
    const float* W_v   = (const float*)d_in[5];
    const float* W_vb  = (const float*)d_in[6];

    char* ws = (char*)d_ws;
    ushort* WvT   = (ushort*)(ws + 0);          //   131072 B
    ushort* WvbT  = (ushort*)(ws + 131072);     //   131072 B
    float*  WqkT  = (float*) (ws + 262144);     //   262144 B
    float*  avg   = (float*) (ws + 524288);     //  1703936 B
    float*  qv    = (float*) (ws + 2228224);    //   851968 B
    float*  kv    = (float*) (ws + 3080192);    //   851968 B
    ushort* vattn = (ushort*)(ws + 3932160);    // 54525952 B
    ushort* Amat  = (ushort*)(ws + 58458112);   //  9437184 B
    ushort* outc  = (ushort*)(ws + 67895296);   // 54525952 B

    k_prep   <<<768,   256, 0, stream>>>(W_qk, W_v, W_vb, WvT, WvbT, WqkT);
    k_projv  <<<1664,  512, 0, stream>>>(x1, x2, WvT, avg, vattn);
    k_qk     <<<1664,  256, 0, stream>>>(avg, WqkT, b_qk, rms_w, qv, kv);
    k_sm_t<1><<<512,   256, 0, stream>>>(qv, kv, Amat);
    k_sm_t<0><<<1152,  256, 0, stream>>>(qv, kv, Amat);
    k_av     <<<1664,  256, 0, stream>>>(Amat, vattn, outc);
    k_out    <<<1664,  256, 0, stream>>>(outc, WvbT, (float*)d_out);
}